// Round 1
// baseline (1622.950 us; speedup 1.0000x reference)
//
#include <hip/hip_runtime.h>
#include <hip/hip_bf16.h>

#define BB 1024
#define TT 512
#define II 128
#define HH 64
#define G4 256   // 4*H
#define EE 128
#define CC 100
#define NB 4     // batch rows per block; 256 blocks = 1 per CU
#define NTH 512

typedef float f2 __attribute__((ext_vector_type(2)));
typedef float f4 __attribute__((ext_vector_type(4)));

__device__ __forceinline__ float sigm(float v) { return 1.f / (1.f + __expf(-v)); }
__device__ __forceinline__ float tanh_f(float v) {
    v = fminf(fmaxf(v, -15.f), 15.f);   // avoid inf/inf NaN
    float e = __expf(2.f * v);
    return (e - 1.f) / (e + 1.f);
}

// Round-3: VGPR_Count=108 with blanket per-iteration "+v" pins proved the
// weights were STILL parked in AGPRs; every pin and every FMA operand was
// serviced by accvgpr_read/write (VALU-busy = 3.2x the pk_fma floor).
// This version:
//  - every MAC is an explicit inline-asm v_pk_fma_f32 with "v" constraints:
//    each USE demands an arch VGPR, so AGPR-parking costs a read per use
//    and buys nothing -> RA should keep the 160 weight floats in VGPRs
//  - k-outer / b-inner loop order: even if AGPR-parked, one accvgpr_read
//    amortizes over NB=4 adjacent uses (caps inflation at ~25%)
//  - NO loop-top pin (removes ~320 junk VALU/step/thread)
#define PKFMA(acc, w, x) asm("v_pk_fma_f32 %0, %1, %2, %0" : "+v"(acc) : "v"(w), "v"(x))

__global__ __launch_bounds__(NTH, 2)
void lstm2_persistent(const float* __restrict__ x,
                      const float* __restrict__ Wih0, const float* __restrict__ Whh0,
                      const float* __restrict__ bih0, const float* __restrict__ bhh0,
                      const float* __restrict__ Wih1, const float* __restrict__ Whh1,
                      const float* __restrict__ bih1, const float* __restrict__ bhh1,
                      float* __restrict__ hlast)
{
    __shared__ float xs[2][NB][II];      // double-buffered x tile (4 KB)
    __shared__ float h0s[NB][HH];        // layer-0 hidden
    __shared__ float h1s[NB][HH];        // layer-1 hidden
    __shared__ float zp0[4][NB][G4];     // layer-0 split-K partials (16 KB)
    __shared__ float zp1[4][NB][G4];     // layer-1 split-K partials (16 KB)
    __shared__ float bs0s[G4], bs1s[G4]; // folded biases

    const int tid = threadIdx.x;
    const int q   = tid >> 7;            // K-quarter 0..3 (wave-uniform)
    const int r   = tid & 127;           // row-pair id: owns gate rows r, r+128
    const int b0  = blockIdx.x * NB;

    // ---- weight fragments: 80 float2 = 160 floats, register-resident ----
    f2 w0a[16], w0b[16];   // Wih0 rows r / r+128, cols [q*32, q*32+32)
    f2 h0a[8],  h0b[8];    // Whh0 rows r / r+128, cols [q*16, q*16+16)
    f2 u1a[8],  u1b[8];    // Wih1 rows r / r+128, cols [q*16, q*16+16)
    f2 v1a[8],  v1b[8];    // Whh1 rows r / r+128, cols [q*16, q*16+16)

#define LOADW(dst, src, n4)                                          \
    do {                                                             \
        const f4* _s = (const f4*)(src);                             \
        _Pragma("unroll")                                            \
        for (int k = 0; k < (n4); ++k) {                             \
            f4 t = _s[k];                                            \
            dst[2*k]   = (f2){t.x, t.y};                             \
            dst[2*k+1] = (f2){t.z, t.w};                             \
        }                                                            \
    } while (0)

    LOADW(w0a, Wih0 + (size_t)r         * II + q * 32, 8);
    LOADW(w0b, Wih0 + (size_t)(r + 128) * II + q * 32, 8);
    LOADW(h0a, Whh0 + (size_t)r         * HH + q * 16, 4);
    LOADW(h0b, Whh0 + (size_t)(r + 128) * HH + q * 16, 4);
    LOADW(u1a, Wih1 + (size_t)r         * HH + q * 16, 4);
    LOADW(u1b, Wih1 + (size_t)(r + 128) * HH + q * 16, 4);
    LOADW(v1a, Whh1 + (size_t)r         * HH + q * 16, 4);
    LOADW(v1b, Whh1 + (size_t)(r + 128) * HH + q * 16, 4);
#undef LOADW

    if (tid < G4) {
        bs0s[tid] = bih0[tid] + bhh0[tid];
        bs1s[tid] = bih1[tid] + bhh1[tid];
        h0s[tid >> 6][tid & 63] = 0.f;
        h1s[tid >> 6][tid & 63] = 0.f;
    }

    // x staging: thread (q, r) loads x[b0+q][t][r] each step; 2-step prefetch
    const float* xrow = x + ((size_t)(b0 + q) * TT) * II + r;
    xs[0][q][r] = xrow[0];
    float pre = xrow[II];                // t = 1

    // combine-stage ownership (tid < 256): cell state lives in these registers
    const int cb = tid >> 6, cj = tid & 63;
    float c0 = 0.f, c1 = 0.f;

    __syncthreads();

    // 3 barriers per step; hazard pairs all cross >=1 barrier (zp0/zp1 are
    // distinct buffers, xs double-buffered; stage-4 writes only h1s which is
    // next read in stage-3 after bar1+bar2).
    for (int t = 0; t < TT; ++t) {
        const int cur = t & 1, nxt = (t + 1) & 1;

        // ---- stage 1: layer-0 partial GEMV (reads xs[cur], h0s; writes zp0) ----
        {
            f2 aA[NB], aB[NB];
            #pragma unroll
            for (int b = 0; b < NB; ++b) { aA[b] = (f2){0.f, 0.f}; aB[b] = (f2){0.f, 0.f}; }

            // x part: k-outer, b-inner (adjacent uses of each weight pair)
            #pragma unroll
            for (int k = 0; k < 8; ++k) {
                f4 vv[NB];
                #pragma unroll
                for (int b = 0; b < NB; ++b)
                    vv[b] = ((const f4*)&xs[cur][b][q * 32])[k];   // wave-uniform -> LDS broadcast
                #pragma unroll
                for (int b = 0; b < NB; ++b) {
                    f2 lo = (f2){vv[b].x, vv[b].y}, hi = (f2){vv[b].z, vv[b].w};
                    PKFMA(aA[b], w0a[2*k],   lo);
                    PKFMA(aA[b], w0a[2*k+1], hi);
                    PKFMA(aB[b], w0b[2*k],   lo);
                    PKFMA(aB[b], w0b[2*k+1], hi);
                }
            }
            // h part
            #pragma unroll
            for (int k = 0; k < 4; ++k) {
                f4 vv[NB];
                #pragma unroll
                for (int b = 0; b < NB; ++b)
                    vv[b] = ((const f4*)&h0s[b][q * 16])[k];
                #pragma unroll
                for (int b = 0; b < NB; ++b) {
                    f2 lo = (f2){vv[b].x, vv[b].y}, hi = (f2){vv[b].z, vv[b].w};
                    PKFMA(aA[b], h0a[2*k],   lo);
                    PKFMA(aA[b], h0a[2*k+1], hi);
                    PKFMA(aB[b], h0b[2*k],   lo);
                    PKFMA(aB[b], h0b[2*k+1], hi);
                }
            }
            #pragma unroll
            for (int b = 0; b < NB; ++b) {
                zp0[q][b][r]       = aA[b].x + aA[b].y;
                zp0[q][b][r + 128] = aB[b].x + aB[b].y;
            }
        }
        __syncthreads();   // bar1

        // ---- stage 2: layer-0 combine + activation + cell update (tid<256) ----
        if (tid < G4) {
            float zi = zp0[0][cb][cj]     + zp0[1][cb][cj]     + zp0[2][cb][cj]     + zp0[3][cb][cj]     + bs0s[cj];
            float zf = zp0[0][cb][64+cj]  + zp0[1][cb][64+cj]  + zp0[2][cb][64+cj]  + zp0[3][cb][64+cj]  + bs0s[64+cj];
            float zg = zp0[0][cb][128+cj] + zp0[1][cb][128+cj] + zp0[2][cb][128+cj] + zp0[3][cb][128+cj] + bs0s[128+cj];
            float zo = zp0[0][cb][192+cj] + zp0[1][cb][192+cj] + zp0[2][cb][192+cj] + zp0[3][cb][192+cj] + bs0s[192+cj];
            float gi = sigm(zi), gf = sigm(zf), gg = tanh_f(zg), go = sigm(zo);
            c0 = gf * c0 + gi * gg;
            h0s[cb][cj] = go * tanh_f(c0);
        }
        __syncthreads();   // bar2

        // ---- stage 3: layer-1 partial GEMV + x staging for t+1 ----
        {
            f2 aA[NB], aB[NB];
            #pragma unroll
            for (int b = 0; b < NB; ++b) { aA[b] = (f2){0.f, 0.f}; aB[b] = (f2){0.f, 0.f}; }

            #pragma unroll
            for (int k = 0; k < 4; ++k) {
                f4 vv[NB];
                #pragma unroll
                for (int b = 0; b < NB; ++b)
                    vv[b] = ((const f4*)&h0s[b][q * 16])[k];
                #pragma unroll
                for (int b = 0; b < NB; ++b) {
                    f2 lo = (f2){vv[b].x, vv[b].y}, hi = (f2){vv[b].z, vv[b].w};
                    PKFMA(aA[b], u1a[2*k],   lo);
                    PKFMA(aA[b], u1a[2*k+1], hi);
                    PKFMA(aB[b], u1b[2*k],   lo);
                    PKFMA(aB[b], u1b[2*k+1], hi);
                }
            }
            #pragma unroll
            for (int k = 0; k < 4; ++k) {
                f4 vv[NB];
                #pragma unroll
                for (int b = 0; b < NB; ++b)
                    vv[b] = ((const f4*)&h1s[b][q * 16])[k];
                #pragma unroll
                for (int b = 0; b < NB; ++b) {
                    f2 lo = (f2){vv[b].x, vv[b].y}, hi = (f2){vv[b].z, vv[b].w};
                    PKFMA(aA[b], v1a[2*k],   lo);
                    PKFMA(aA[b], v1a[2*k+1], hi);
                    PKFMA(aB[b], v1b[2*k],   lo);
                    PKFMA(aB[b], v1b[2*k+1], hi);
                }
            }
            #pragma unroll
            for (int b = 0; b < NB; ++b) {
                zp1[q][b][r]       = aA[b].x + aA[b].y;
                zp1[q][b][r + 128] = aB[b].x + aB[b].y;
            }
        }
        xs[nxt][q][r] = pre;
        {
            int tn = (t + 2 < TT) ? t + 2 : TT - 1;
            pre = xrow[(size_t)tn * II];
        }
        __syncthreads();   // bar3

        // ---- stage 4: layer-1 combine + cell update (tid<256), no barrier ----
        if (tid < G4) {
            float zi = zp1[0][cb][cj]     + zp1[1][cb][cj]     + zp1[2][cb][cj]     + zp1[3][cb][cj]     + bs1s[cj];
            float zf = zp1[0][cb][64+cj]  + zp1[1][cb][64+cj]  + zp1[2][cb][64+cj]  + zp1[3][cb][64+cj]  + bs1s[64+cj];
            float zg = zp1[0][cb][128+cj] + zp1[1][cb][128+cj] + zp1[2][cb][128+cj] + zp1[3][cb][128+cj] + bs1s[128+cj];
            float zo = zp1[0][cb][192+cj] + zp1[1][cb][192+cj] + zp1[2][cb][192+cj] + zp1[3][cb][192+cj] + bs1s[192+cj];
            float gi = sigm(zi), gf = sigm(zf), gg = tanh_f(zg), go = sigm(zo);
            c1 = gf * c1 + gi * gg;
            h1s[cb][cj] = go * tanh_f(c1);
        }
    }
#undef PKFMA

    // stage-4 thread wrote h1s[cb][cj] itself -> read-own-write, no barrier
    if (tid < G4) hlast[(size_t)(b0 + cb) * HH + cj] = h1s[cb][cj];
}

// MLP head: one block per batch row. relu(hW_p^T+b) -> relu(.W_1^T+b) -> .W_2^T+b
__global__ __launch_bounds__(128, 4)
void head_kernel(const float* __restrict__ hlast,
                 const float* __restrict__ Wp, const float* __restrict__ bp,
                 const float* __restrict__ W1, const float* __restrict__ b1,
                 const float* __restrict__ W2, const float* __restrict__ b2,
                 float* __restrict__ out)
{
    __shared__ float hv[HH];
    __shared__ float emb[EE];
    __shared__ float hid[EE];
    const int b = blockIdx.x;
    const int e = threadIdx.x;   // 0..127
    if (e < HH) hv[e] = hlast[(size_t)b * HH + e];
    __syncthreads();
    float z = bp[e];
    #pragma unroll
    for (int j = 0; j < HH; ++j) z += Wp[e * HH + j] * hv[j];
    emb[e] = fmaxf(z, 0.f);
    __syncthreads();
    z = b1[e];
    #pragma unroll
    for (int j = 0; j < EE; ++j) z += W1[e * EE + j] * emb[j];
    hid[e] = fmaxf(z, 0.f);
    __syncthreads();
    if (e < CC) {
        z = b2[e];
        #pragma unroll
        for (int j = 0; j < EE; ++j) z += W2[e * EE + j] * hid[j];
        out[(size_t)b * CC + e] = z;
    }
}

extern "C" void kernel_launch(void* const* d_in, const int* in_sizes, int n_in,
                              void* d_out, int out_size, void* d_ws, size_t ws_size,
                              hipStream_t stream)
{
    const float* x    = (const float*)d_in[0];
    const float* Wih0 = (const float*)d_in[1];
    const float* Whh0 = (const float*)d_in[2];
    const float* bih0 = (const float*)d_in[3];
    const float* bhh0 = (const float*)d_in[4];
    const float* Wih1 = (const float*)d_in[5];
    const float* Whh1 = (const float*)d_in[6];
    const float* bih1 = (const float*)d_in[7];
    const float* bhh1 = (const float*)d_in[8];
    const float* Wp   = (const float*)d_in[9];
    const float* bp   = (const float*)d_in[10];
    const float* W1   = (const float*)d_in[11];
    const float* b1   = (const float*)d_in[12];
    const float* W2   = (const float*)d_in[13];
    const float* b2   = (const float*)d_in[14];

    float* hlast = (float*)d_ws;           // 1024*64 fp32 = 256 KB
    float* out   = (float*)d_out;          // [1024, 100] fp32

    lstm2_persistent<<<BB / NB, NTH, 0, stream>>>(x, Wih0, Whh0, bih0, bhh0,
                                                  Wih1, Whh1, bih1, bhh1, hlast);
    head_kernel<<<BB, EE, 0, stream>>>(hlast, Wp, bp, W1, b1, W2, b2, out);
}

// Round 3
// 1502.642 us; speedup vs baseline: 1.0801x; 1.0801x over previous
//
#include <hip/hip_runtime.h>
#include <hip/hip_bf16.h>

#define BB 1024
#define TT 512
#define II 128
#define HH 64
#define G4 256   // 4*H
#define EE 128
#define CC 100
#define NB 4     // batch rows per block; 256 blocks = 1 per CU
#define NTH 512

typedef float f2 __attribute__((ext_vector_type(2)));
typedef float f4 __attribute__((ext_vector_type(4)));

__device__ __forceinline__ float sigm(float v) { return 1.f / (1.f + __expf(-v)); }
__device__ __forceinline__ float tanh_f(float v) {
    v = fminf(fmaxf(v, -15.f), 15.f);   // avoid inf/inf NaN
    float e = __expf(2.f * v);
    return (e - 1.f) / (e + 1.f);
}

// Round-5 (resubmit of round-4; bench infra failed, kernel never ran).
// Cross-layer software pipeline: L1's GEMV for step t-1 runs alongside L0's
// GEMV for step t (L1 needs h0(t-1), h1(t-2) -- both ready), then ONE fused
// combine where waves 0-3 update cell0(t) and waves 4-7 update cell1(t-1)
// concurrently. 2 barriers/iter (was 3), one full-occupancy combine (was two
// half-occupancy serial ones). GEMV bodies = round-0 codegen (best measured).
__global__ __launch_bounds__(NTH, 2)
void lstm2_persistent(const float* __restrict__ x,
                      const float* __restrict__ Wih0, const float* __restrict__ Whh0,
                      const float* __restrict__ bih0, const float* __restrict__ bhh0,
                      const float* __restrict__ Wih1, const float* __restrict__ Whh1,
                      const float* __restrict__ bih1, const float* __restrict__ bhh1,
                      float* __restrict__ hlast)
{
    __shared__ float xs[2][NB][II];      // double-buffered x tile (4 KB)
    __shared__ float h0s[NB][HH];        // layer-0 hidden h0(t-1)
    __shared__ float h1s[NB][HH];        // layer-1 hidden h1(t-2)
    __shared__ float zp0[4][NB][G4];     // layer-0 split-K partials (16 KB)
    __shared__ float zp1[4][NB][G4];     // layer-1 split-K partials (16 KB)
    __shared__ float bs0s[G4], bs1s[G4]; // folded biases

    const int tid = threadIdx.x;
    const int q   = tid >> 7;            // K-quarter 0..3 (wave-uniform)
    const int r   = tid & 127;           // row-pair id: owns gate rows r, r+128
    const int b0  = blockIdx.x * NB;

    // ---- weight fragments: 80 float2 = 160 floats ----
    f2 w0a[16], w0b[16];   // Wih0 rows r / r+128, cols [q*32, q*32+32)
    f2 h0a[8],  h0b[8];    // Whh0 rows r / r+128, cols [q*16, q*16+16)
    f2 u1a[8],  u1b[8];    // Wih1 rows r / r+128, cols [q*16, q*16+16)
    f2 v1a[8],  v1b[8];    // Whh1 rows r / r+128, cols [q*16, q*16+16)

#define LOADW(dst, src, n4)                                          \
    do {                                                             \
        const f4* _s = (const f4*)(src);                             \
        _Pragma("unroll")                                            \
        for (int k = 0; k < (n4); ++k) {                             \
            f4 t = _s[k];                                            \
            dst[2*k]   = (f2){t.x, t.y};                             \
            dst[2*k+1] = (f2){t.z, t.w};                             \
        }                                                            \
    } while (0)

    LOADW(w0a, Wih0 + (size_t)r         * II + q * 32, 8);
    LOADW(w0b, Wih0 + (size_t)(r + 128) * II + q * 32, 8);
    LOADW(h0a, Whh0 + (size_t)r         * HH + q * 16, 4);
    LOADW(h0b, Whh0 + (size_t)(r + 128) * HH + q * 16, 4);
    LOADW(u1a, Wih1 + (size_t)r         * HH + q * 16, 4);
    LOADW(u1b, Wih1 + (size_t)(r + 128) * HH + q * 16, 4);
    LOADW(v1a, Whh1 + (size_t)r         * HH + q * 16, 4);
    LOADW(v1b, Whh1 + (size_t)(r + 128) * HH + q * 16, 4);
#undef LOADW

#define PIN(arr, n)                                                  \
    _Pragma("unroll")                                                \
    for (int _i = 0; _i < (n); ++_i) asm volatile("" : "+v"(arr[_i]))

    if (tid < G4) {
        bs0s[tid] = bih0[tid] + bhh0[tid];
        bs1s[tid] = bih1[tid] + bhh1[tid];
        h0s[tid >> 6][tid & 63] = 0.f;
        h1s[tid >> 6][tid & 63] = 0.f;
    }

    // x staging: thread (q, r) loads x[b0+q][t][r] each step; 2-step prefetch
    const float* xrow = x + ((size_t)(b0 + q) * TT) * II + r;
    xs[0][q][r] = xrow[0];
    float pre = xrow[II];                // x(1)

    // combine ownership: waves 0-3 (tid<256) own cell0(b=cb,j=cj),
    // waves 4-7 (tid>=256) own cell1(b=cb,j=cj)
    const int cb = (tid >> 6) & 3, cj = tid & 63;
    float c0 = 0.f, c1 = 0.f;

    __syncthreads();

    // Pipelined: iteration t computes z0(t) [t<TT] and z1(t-1) [t>=1] in one
    // GEMV stage, then one fused combine. Hazards:
    //   GEMV reads h0s/h1s, combine writes them  -> bar1 between
    //   combine reads zp*, next GEMV writes zp*  -> bar2 between
    for (int t = 0; t <= TT; ++t) {
        const int cur = t & 1, nxt = cur ^ 1;

        // re-pin every iteration (best-measured codegen config)
        PIN(w0a, 16); PIN(w0b, 16);
        PIN(h0a, 8);  PIN(h0b, 8);
        PIN(u1a, 8);  PIN(u1b, 8);
        PIN(v1a, 8);  PIN(v1b, 8);

        // ---- fused GEMV stage ----
        if (t < TT) {   // layer-0 partial GEMV for step t
            f2 aA[NB], aB[NB];
            #pragma unroll
            for (int b = 0; b < NB; ++b) { aA[b] = (f2){0.f, 0.f}; aB[b] = (f2){0.f, 0.f}; }
            #pragma unroll
            for (int b = 0; b < NB; ++b) {
                const f4* xv = (const f4*)&xs[cur][b][q * 32];
                #pragma unroll
                for (int k = 0; k < 8; ++k) {
                    f4 v = xv[k];                       // wave-uniform -> LDS broadcast
                    f2 lo = (f2){v.x, v.y}, hi = (f2){v.z, v.w};
                    aA[b] += w0a[2*k] * lo;  aA[b] += w0a[2*k+1] * hi;
                    aB[b] += w0b[2*k] * lo;  aB[b] += w0b[2*k+1] * hi;
                }
                const f4* hv = (const f4*)&h0s[b][q * 16];
                #pragma unroll
                for (int k = 0; k < 4; ++k) {
                    f4 v = hv[k];
                    f2 lo = (f2){v.x, v.y}, hi = (f2){v.z, v.w};
                    aA[b] += h0a[2*k] * lo;  aA[b] += h0a[2*k+1] * hi;
                    aB[b] += h0b[2*k] * lo;  aB[b] += h0b[2*k+1] * hi;
                }
            }
            #pragma unroll
            for (int b = 0; b < NB; ++b) {
                zp0[q][b][r]       = aA[b].x + aA[b].y;
                zp0[q][b][r + 128] = aB[b].x + aB[b].y;
            }
        }
        if (t >= 1) {   // layer-1 partial GEMV for step t-1 (uses h0(t-1), h1(t-2))
            f2 aA[NB], aB[NB];
            #pragma unroll
            for (int b = 0; b < NB; ++b) { aA[b] = (f2){0.f, 0.f}; aB[b] = (f2){0.f, 0.f}; }
            #pragma unroll
            for (int b = 0; b < NB; ++b) {
                const f4* hv0 = (const f4*)&h0s[b][q * 16];
                #pragma unroll
                for (int k = 0; k < 4; ++k) {
                    f4 v = hv0[k];
                    f2 lo = (f2){v.x, v.y}, hi = (f2){v.z, v.w};
                    aA[b] += u1a[2*k] * lo;  aA[b] += u1a[2*k+1] * hi;
                    aB[b] += u1b[2*k] * lo;  aB[b] += u1b[2*k+1] * hi;
                }
                const f4* hv1 = (const f4*)&h1s[b][q * 16];
                #pragma unroll
                for (int k = 0; k < 4; ++k) {
                    f4 v = hv1[k];
                    f2 lo = (f2){v.x, v.y}, hi = (f2){v.z, v.w};
                    aA[b] += v1a[2*k] * lo;  aA[b] += v1a[2*k+1] * hi;
                    aB[b] += v1b[2*k] * lo;  aB[b] += v1b[2*k+1] * hi;
                }
            }
            #pragma unroll
            for (int b = 0; b < NB; ++b) {
                zp1[q][b][r]       = aA[b].x + aA[b].y;
                zp1[q][b][r + 128] = aB[b].x + aB[b].y;
            }
        }
        // x staging for t+1 (overlaps GEMV tail)
        if (t < TT - 1) {
            xs[nxt][q][r] = pre;
            int tn = (t + 2 < TT) ? t + 2 : TT - 1;
            pre = xrow[(size_t)tn * II];
        }
        __syncthreads();   // bar1: zp*/h* handoff to combine

        // ---- fused combine: waves 0-3 -> cell0(t), waves 4-7 -> cell1(t-1) ----
        if (tid < G4) {
            if (t < TT) {
                float zi = zp0[0][cb][cj]     + zp0[1][cb][cj]     + zp0[2][cb][cj]     + zp0[3][cb][cj]     + bs0s[cj];
                float zf = zp0[0][cb][64+cj]  + zp0[1][cb][64+cj]  + zp0[2][cb][64+cj]  + zp0[3][cb][64+cj]  + bs0s[64+cj];
                float zg = zp0[0][cb][128+cj] + zp0[1][cb][128+cj] + zp0[2][cb][128+cj] + zp0[3][cb][128+cj] + bs0s[128+cj];
                float zo = zp0[0][cb][192+cj] + zp0[1][cb][192+cj] + zp0[2][cb][192+cj] + zp0[3][cb][192+cj] + bs0s[192+cj];
                float gi = sigm(zi), gf = sigm(zf), gg = tanh_f(zg), go = sigm(zo);
                c0 = gf * c0 + gi * gg;
                h0s[cb][cj] = go * tanh_f(c0);
            }
        } else {
            if (t >= 1) {
                float zi = zp1[0][cb][cj]     + zp1[1][cb][cj]     + zp1[2][cb][cj]     + zp1[3][cb][cj]     + bs1s[cj];
                float zf = zp1[0][cb][64+cj]  + zp1[1][cb][64+cj]  + zp1[2][cb][64+cj]  + zp1[3][cb][64+cj]  + bs1s[64+cj];
                float zg = zp1[0][cb][128+cj] + zp1[1][cb][128+cj] + zp1[2][cb][128+cj] + zp1[3][cb][128+cj] + bs1s[128+cj];
                float zo = zp1[0][cb][192+cj] + zp1[1][cb][192+cj] + zp1[2][cb][192+cj] + zp1[3][cb][192+cj] + bs1s[192+cj];
                float gi = sigm(zi), gf = sigm(zf), gg = tanh_f(zg), go = sigm(zo);
                c1 = gf * c1 + gi * gg;
                h1s[cb][cj] = go * tanh_f(c1);
            }
        }
        __syncthreads();   // bar2: h* handoff to next GEMV / zp* reuse
    }
#undef PIN

    // the combine thread wrote h1s[cb][cj] itself at iteration TT -> read-own-write
    if (tid >= G4) hlast[(size_t)(b0 + cb) * HH + cj] = h1s[cb][cj];
}

// MLP head: one block per batch row. relu(hW_p^T+b) -> relu(.W_1^T+b) -> .W_2^T+b
__global__ __launch_bounds__(128, 4)
void head_kernel(const float* __restrict__ hlast,
                 const float* __restrict__ Wp, const float* __restrict__ bp,
                 const float* __restrict__ W1, const float* __restrict__ b1,
                 const float* __restrict__ W2, const float* __restrict__ b2,
                 float* __restrict__ out)
{
    __shared__ float hv[HH];
    __shared__ float emb[EE];
    __shared__ float hid[EE];
    const int b = blockIdx.x;
    const int e = threadIdx.x;   // 0..127
    if (e < HH) hv[e] = hlast[(size_t)b * HH + e];
    __syncthreads();
    float z = bp[e];
    #pragma unroll
    for (int j = 0; j < HH; ++j) z += Wp[e * HH + j] * hv[j];
    emb[e] = fmaxf(z, 0.f);
    __syncthreads();
    z = b1[e];
    #pragma unroll
    for (int j = 0; j < EE; ++j) z += W1[e * EE + j] * emb[j];
    hid[e] = fmaxf(z, 0.f);
    __syncthreads();
    if (e < CC) {
        z = b2[e];
        #pragma unroll
        for (int j = 0; j < EE; ++j) z += W2[e * EE + j] * hid[j];
        out[(size_t)b * CC + e] = z;
    }
}

extern "C" void kernel_launch(void* const* d_in, const int* in_sizes, int n_in,
                              void* d_out, int out_size, void* d_ws, size_t ws_size,
                              hipStream_t stream)
{
    const float* x    = (const float*)d_in[0];
    const float* Wih0 = (const float*)d_in[1];
    const float* Whh0 = (const float*)d_in[2];
    const float* bih0 = (const float*)d_in[3];
    const float* bhh0 = (const float*)d_in[4];
    const float* Wih1 = (const float*)d_in[5];
    const float* Whh1 = (const float*)d_in[6];
    const float* bih1 = (const float*)d_in[7];
    const float* bhh1 = (const float*)d_in[8];
    const float* Wp   = (const float*)d_in[9];
    const float* bp   = (const float*)d_in[10];
    const float* W1   = (const float*)d_in[11];
    const float* b1   = (const float*)d_in[12];
    const float* W2   = (const float*)d_in[13];
    const float* b2   = (const float*)d_in[14];

    float* hlast = (float*)d_ws;           // 1024*64 fp32 = 256 KB
    float* out   = (float*)d_out;          // [1024, 100] fp32

    lstm2_persistent<<<BB / NB, NTH, 0, stream>>>(x, Wih0, Whh0, bih0, bhh0,
                                                  Wih1, Whh1, bih1, bhh1, hlast);
    head_kernel<<<BB, EE, 0, stream>>>(hlast, Wp, bp, W1, b1, W2, b2, out);
}